// Round 1
// baseline (243.709 us; speedup 1.0000x reference)
//
#include <hip/hip_runtime.h>
#include <hip/hip_bf16.h>

#define B_   8
#define N_   2048
#define FIN  128
#define OUTD 256
#define H_   4
#define LOG2E 1.44269504088896340736f

typedef __bf16 bf16x8 __attribute__((ext_vector_type(8)));
typedef float  f32x4  __attribute__((ext_vector_type(4)));

// ---------------- kernel 1: fp32 -> bf16 for X and W ----------------
__global__ __launch_bounds__(256) void conv_bf16(const float* __restrict__ X,
                                                 const float* __restrict__ W,
                                                 unsigned short* __restrict__ Xb,
                                                 unsigned short* __restrict__ Wb) {
    const int NX4 = (B_ * N_ * FIN) / 4;   // 524288 float4 groups in X
    int i = blockIdx.x * 256 + threadIdx.x;
    const float4* src;
    ushort4* dst;
    int idx;
    if (i < NX4) { src = (const float4*)X; dst = (ushort4*)Xb; idx = i; }
    else         { src = (const float4*)W; dst = (ushort4*)Wb; idx = i - NX4; }
    float4 v = src[idx];
    __hip_bfloat16 b0 = __float2bfloat16(v.x);
    __hip_bfloat16 b1 = __float2bfloat16(v.y);
    __hip_bfloat16 b2 = __float2bfloat16(v.z);
    __hip_bfloat16 b3 = __float2bfloat16(v.w);
    ushort4 o;
    o.x = *(unsigned short*)&b0;
    o.y = *(unsigned short*)&b1;
    o.z = *(unsigned short*)&b2;
    o.w = *(unsigned short*)&b3;
    dst[idx] = o;
}

// ---------------- kernel 2: X_trans = X @ W.T via bf16 MFMA ----------------
// grid (1024, 4), block 256 (4 waves). Each wave: one 16x16 output tile.
// A-frag: A[m=lane&15][k=(lane>>4)*8+j]; B-frag: B[k=(lane>>4)*8+j][n=lane&15]
// with B[k][n] = W[n][k]. C/D: col=lane&15, row=(lane>>4)*4+reg (verified m89/m91).
__global__ __launch_bounds__(256) void gemm_bf16(const unsigned short* __restrict__ Xb,
                                                 const unsigned short* __restrict__ Wb,
                                                 float* __restrict__ Xt) {
    int r0   = blockIdx.x * 16;                 // row tile
    int wave = threadIdx.x >> 6;
    int lane = threadIdx.x & 63;
    int c0   = (blockIdx.y * 4 + wave) * 16;    // channel tile
    int m = lane & 15, q = lane >> 4;

    const bf16x8* Arow = (const bf16x8*)(Xb + (size_t)(r0 + m) * FIN);
    const bf16x8* Brow = (const bf16x8*)(Wb + (size_t)(c0 + m) * FIN);
    f32x4 acc = {0.f, 0.f, 0.f, 0.f};
#pragma unroll
    for (int kc = 0; kc < 4; ++kc) {            // K = 128 = 4 x 32
        bf16x8 af = Arow[kc * 4 + q];
        bf16x8 bf = Brow[kc * 4 + q];
        acc = __builtin_amdgcn_mfma_f32_16x16x32_bf16(af, bf, acc, 0, 0, 0);
    }
    float* outp = Xt + (size_t)(r0 + q * 4) * OUTD + c0 + m;
#pragma unroll
    for (int reg = 0; reg < 4; ++reg)
        outp[(size_t)reg * OUTD] = acc[reg];
}

// ---------------- kernel 3: s,t = einsum('bnhd,hd->bnh'), pre-scaled by log2(e) ----
// one wave per row (lane = d), grid 4096 x 4 waves
__global__ __launch_bounds__(256) void st_kernel(const float* __restrict__ Xt,
                                                 const float* __restrict__ a_src,
                                                 const float* __restrict__ a_dst,
                                                 float* __restrict__ s_arr,
                                                 float* __restrict__ t_arr) {
    int row  = blockIdx.x * 4 + (threadIdx.x >> 6);
    int lane = threadIdx.x & 63;
    const float* xr = Xt + (size_t)row * OUTD;
#pragma unroll
    for (int h = 0; h < H_; ++h) {
        float v  = xr[h * 64 + lane];
        float vs = v * a_src[h * 64 + lane];
        float vd = v * a_dst[h * 64 + lane];
#pragma unroll
        for (int off = 32; off > 0; off >>= 1) {
            vs += __shfl_down(vs, off);
            vd += __shfl_down(vd, off);
        }
        if (lane == 0) {
            s_arr[(size_t)row * H_ + h] = vs * LOG2E;
            t_arr[(size_t)row * H_ + h] = vd * LOG2E;
        }
    }
}

// ---------------- kernel 4: masked-softmax diagonal + output scale ----------------
// grid 1024 (= 8 b * 128 row-tiles), block 256. 16 rows/block, 16 lanes per row.
// LDS: t' for the whole graph b (2048x4 fp32 = 32 KB) -> 4 blocks/CU.
__global__ __launch_bounds__(256) void gat_main(const float* __restrict__ A,
                                                const float* __restrict__ s_arr,
                                                const float* __restrict__ t_arr,
                                                float* __restrict__ out) {
    __shared__ float t_lds[N_ * H_];            // 32 KB
    __shared__ float diag_lds[16][H_];

    int b  = blockIdx.x >> 7;
    int rt = blockIdx.x & 127;
    int r0 = rt * 16;
    int tid = threadIdx.x;

    // stage t' table for graph b
    {
        const float4* tsrc = (const float4*)(t_arr + (size_t)b * N_ * H_);
        float4* tdst = (float4*)t_lds;
        for (int i = tid; i < (N_ * H_) / 4; i += 256) tdst[i] = tsrc[i];
    }
    __syncthreads();

    int r  = tid >> 4;          // 0..15 row within tile
    int lj = tid & 15;          // 16 lanes sweep j
    int gi = r0 + r;            // row index within graph b

    f32x4 s4 = *(const f32x4*)(s_arr + ((size_t)b * N_ + gi) * H_);
    const float* Arow = A + ((size_t)b * N_ + gi) * N_;

    float acc0 = 0.f, acc1 = 0.f, acc2 = 0.f, acc3 = 0.f;
    for (int it = 0; it < N_ / 64; ++it) {
        int j = it * 64 + lj * 4;
        float4 a4 = *(const float4*)(Arow + j);
#pragma unroll
        for (int jj = 0; jj < 4; ++jj) {
            f32x4 t4 = ((const f32x4*)t_lds)[j + jj];
            float aj = (jj == 0) ? a4.x : (jj == 1) ? a4.y : (jj == 2) ? a4.z : a4.w;
            float y0 = s4[0] + t4[0]; y0 = fmaxf(y0, 0.2f * y0); acc0 = fmaf(aj, exp2f(y0), acc0);
            float y1 = s4[1] + t4[1]; y1 = fmaxf(y1, 0.2f * y1); acc1 = fmaf(aj, exp2f(y1), acc1);
            float y2 = s4[2] + t4[2]; y2 = fmaxf(y2, 0.2f * y2); acc2 = fmaf(aj, exp2f(y2), acc2);
            float y3 = s4[3] + t4[3]; y3 = fmaxf(y3, 0.2f * y3); acc3 = fmaf(aj, exp2f(y3), acc3);
        }
    }
    // reduce across the 16 lanes of this row
#pragma unroll
    for (int mk = 8; mk > 0; mk >>= 1) {
        acc0 += __shfl_xor(acc0, mk);
        acc1 += __shfl_xor(acc1, mk);
        acc2 += __shfl_xor(acc2, mk);
        acc3 += __shfl_xor(acc3, mk);
    }
    if (lj == 0) {
        f32x4 ti = ((const f32x4*)t_lds)[gi];
        float y, e;
        y = s4[0] + ti[0]; y = fmaxf(y, 0.2f * y); e = exp2f(y); diag_lds[r][0] = e / acc0;
        y = s4[1] + ti[1]; y = fmaxf(y, 0.2f * y); e = exp2f(y); diag_lds[r][1] = e / acc1;
        y = s4[2] + ti[2]; y = fmaxf(y, 0.2f * y); e = exp2f(y); diag_lds[r][2] = e / acc2;
        y = s4[3] + ti[3]; y = fmaxf(y, 0.2f * y); e = exp2f(y); diag_lds[r][3] = e / acc3;
    }
    __syncthreads();

    // epilogue: out = diag * X_trans (in place; X_trans lives in d_out)
    float* orow = out + ((size_t)b * N_ + gi) * OUTD;
#pragma unroll
    for (int ii = 0; ii < 4; ++ii) {
        int c = lj * 4 + ii * 64;               // head h == ii (lj*4 < 64)
        float4 v = *(float4*)(orow + c);
        float dg = diag_lds[r][ii];
        v.x *= dg; v.y *= dg; v.z *= dg; v.w *= dg;
        *(float4*)(orow + c) = v;
    }
}

extern "C" void kernel_launch(void* const* d_in, const int* in_sizes, int n_in,
                              void* d_out, int out_size, void* d_ws, size_t ws_size,
                              hipStream_t stream) {
    const float* A     = (const float*)d_in[0];
    const float* X     = (const float*)d_in[1];
    const float* W     = (const float*)d_in[2];
    const float* a_src = (const float*)d_in[3];
    const float* a_dst = (const float*)d_in[4];
    float* out = (float*)d_out;

    // workspace carve-up (~4.8 MB total)
    char* ws = (char*)d_ws;
    unsigned short* Xb = (unsigned short*)ws;                 // 4,194,304 B
    unsigned short* Wb = (unsigned short*)(ws + 4194304);     //    65,536 B
    float* s_arr = (float*)(ws + 4259840);                    //   262,144 B
    float* t_arr = (float*)(ws + 4521984);                    //   262,144 B

    // 1) cast X, W to bf16
    conv_bf16<<<2080, 256, 0, stream>>>(X, W, Xb, Wb);
    // 2) X_trans = X @ W.T  (written into d_out, scaled in place later)
    gemm_bf16<<<dim3(1024, 4), 256, 0, stream>>>(Xb, Wb, out);
    // 3) attention source/dest logits (pre-scaled by log2 e)
    st_kernel<<<4096, 256, 0, stream>>>(out, a_src, a_dst, s_arr, t_arr);
    // 4) masked softmax diagonal + scale
    gat_main<<<1024, 256, 0, stream>>>(A, s_arr, t_arr, out);
}